// Round 15
// baseline (8167.923 us; speedup 1.0000x reference)
//
#include <hip/hip_runtime.h>
#include <math.h>

#define TT 2048
#define BB 32
#define HH 512

typedef float f32x4 __attribute__((ext_vector_type(4)));
typedef float f32x2 __attribute__((ext_vector_type(2)));

// ---------------- input-projection GEMM: OUT[r,:] = X[r,:]@W + bias ----------------
template<int K>
__global__ void __launch_bounds__(256)
ih_gemm(const float* X, const float* __restrict__ W,
        const float* __restrict__ bias, float* OUT)
{
    __shared__ float xt[32][K];
    const int wg  = (int)blockIdx.x;
    const int tid = (int)threadIdx.x;
    const long row0 = (long)wg * 32;

    {   // stage 32 rows of X (coalesced 16B, non-temporal)
        const f32x4* Xv = (const f32x4*)(X + row0 * K);
        f32x4* xtv = (f32x4*)(&xt[0][0]);
        const int n4 = 8 * K;
        for (int i = tid; i < n4; i += 256) xtv[i] = __builtin_nontemporal_load(&Xv[i]);
    }
    __syncthreads();

    const int j2 = tid * 2;
    float acc0[32], acc1[32];
    #pragma unroll
    for (int r = 0; r < 32; ++r) { acc0[r] = 0.f; acc1[r] = 0.f; }

    for (int k = 0; k < K; k += 4) {
        const float2 w0 = *(const float2*)&W[(k+0)*HH + j2];
        const float2 w1 = *(const float2*)&W[(k+1)*HH + j2];
        const float2 w2 = *(const float2*)&W[(k+2)*HH + j2];
        const float2 w3 = *(const float2*)&W[(k+3)*HH + j2];
        #pragma unroll
        for (int r = 0; r < 32; ++r) {
            const float4 xv = *(const float4*)&xt[r][k];
            acc0[r] += xv.x*w0.x + xv.y*w1.x + xv.z*w2.x + xv.w*w3.x;
            acc1[r] += xv.x*w0.y + xv.y*w1.y + xv.z*w2.y + xv.w*w3.y;
        }
    }
    const float2 bv = *(const float2*)&bias[j2];
    #pragma unroll
    for (int r = 0; r < 32; ++r) {
        f32x2 o; o.x = acc0[r] + bv.x; o.y = acc1[r] + bv.y;
        __builtin_nontemporal_store(o, (f32x2*)&OUT[(row0 + r) * HH + j2]);
    }
}

// ---------------- fused 2-layer persistent recurrence ----------------
// r12 structure/schedule (PASSED; tag-chain + parity-LDS proofs unchanged), plus the
// XCD-local L2 comm fast path:
//  - Publish DOUBLE: sc0 store into hbL2 (stays dirty in the publisher XCD's L2,
//    visible to same-XCD CUs at ~200cy) AND the proven agent-scope store into hbG
//    (L3/IF coherence point, visible everywhere, ~900cy). Chain c's 8 WGs have
//    bid%8 == c%8 -> same XCD under round-robin; if that heuristic EVER fails, the
//    agent copy keeps us correct (consumers fall back after 10 fast tries).
//  - Fast poll: flat_load sc0 + s_waitcnt lgkmcnt(0). flat bumps vmcnt AND lgkmcnt;
//    waiting lgkm-only means polls do NOT drain wave0's in-flight global pre-loads
//    (vmcnt) -> the pre prefetch keeps its full superstep of latency distance.
//  - Stale hbL2 tags across graph replays alias this replay's tags, but inputs are
//    identical across replays -> same tag implies same value: benign. First call
//    sees 0xAA poison (tag 0xAAAAAAAA never matches) or the memset zeros.
static __device__ __forceinline__ float tanhx(float s) {
    const float e = __expf(2.0f * s);
    return 1.0f - 2.0f / (e + 1.0f);
}
static __device__ __forceinline__ void pub2(unsigned long long* pL2,
                                            unsigned long long* pG,
                                            unsigned tag, float v) {
    const unsigned long long pk =
        ((unsigned long long)tag << 32) | (unsigned long long)__float_as_uint(v);
    asm volatile("global_store_dwordx2 %0, %1, off sc0" :: "v"(pL2), "v"(pk) : "memory");
    __hip_atomic_store(pG, pk, __ATOMIC_RELAXED, __HIP_MEMORY_SCOPE_AGENT);
}
static __device__ __forceinline__ float poll2(unsigned long long* pL2,
                                              unsigned long long* pG, unsigned want) {
    unsigned long long pk;
    #pragma unroll 1
    for (int i = 0; i < 10; ++i) {   // fast path: same-XCD L2
        asm volatile("flat_load_dwordx2 %0, %1 sc0\n\ts_waitcnt lgkmcnt(0)"
                     : "=v"(pk) : "v"(pL2) : "memory");
        if ((unsigned)(pk >> 32) == want)
            return __uint_as_float((unsigned)pk);
    }
    pk = __hip_atomic_load(pG, __ATOMIC_RELAXED, __HIP_MEMORY_SCOPE_AGENT);
    while ((unsigned)(pk >> 32) != want)   // fallback: agent scope, always correct
        pk = __hip_atomic_load(pG, __ATOMIC_RELAXED, __HIP_MEMORY_SCOPE_AGENT);
    return __uint_as_float((unsigned)pk);
}

__global__ void __attribute__((amdgpu_flat_work_group_size(512, 512),
                               amdgpu_waves_per_eu(2, 2)))
fused_recur(const float* __restrict__ Whh0, const float* __restrict__ Wih1,
            const float* __restrict__ Whh1, const float* __restrict__ b1,
            float* __restrict__ seq, float* __restrict__ hTout,
            unsigned long long* __restrict__ hb)
{
    __shared__ float lds_w[HH][64];        // Whh1 slice: [k][j-local], 128 KB
    __shared__ float lds_a[2][8][64];      // C1 partials (parity dbuf)
    __shared__ float lds_b[2][8][64];      // C2 partials (parity dbuf)
    const int bid  = (int)blockIdx.x;
    const int c    = bid & 31;      // chain; its 8 WGs share bid%8 -> same XCD (heuristic)
    const int x    = bid >> 5;      // col-slice 0..7
    const int tid  = (int)threadIdx.x;
    const int lane = tid & 63;
    const int w    = tid >> 6;      // wave id == k-group
    const int J    = (x << 6) + lane;
    const long wb  = (long)(w << 6) * HH + J;

    // hb regions: [0]=G0 [32K]=G1 [64K]=L2_0 [96K]=L2_1 (slots of 8B; 256KB each)
    unsigned long long* hbG0 = hb            + c * (2 * HH);
    unsigned long long* hbG1 = hb + 32768    + c * (2 * HH);
    unsigned long long* hbL0 = hb + 65536    + c * (2 * HH);
    unsigned long long* hbL1 = hb + 98304    + c * (2 * HH);

    // ---- stage Whh1 slice into LDS (one-time, coalesced float4) ----
    {
        const int x64 = x << 6;
        for (int idx = tid; idx < HH * 16; idx += 512) {
            const int k  = idx >> 4;
            const int j4 = (idx & 15) << 2;
            *(float4*)&lds_w[k][j4] = *(const float4*)&Whh1[(long)k * HH + x64 + j4];
        }
    }

    // ---- Whh0 (wa*) + Wih1 (wi*): 32 named float4s, pinned arch VGPRs ----
    float4 wa0,wa1,wa2,wa3,wa4,wa5,wa6,wa7,wa8,wa9,wa10,wa11,wa12,wa13,wa14,wa15;
    float4 wi0,wi1,wi2,wi3,wi4,wi5,wi6,wi7,wi8,wi9,wi10,wi11,wi12,wi13,wi14,wi15;
#define LD1(P, M, q) do { \
        P##q.x = M[wb + (4*q+0)*HH]; P##q.y = M[wb + (4*q+1)*HH]; \
        P##q.z = M[wb + (4*q+2)*HH]; P##q.w = M[wb + (4*q+3)*HH]; } while (0)
    LD1(wa,Whh0,0);  LD1(wa,Whh0,1);  LD1(wa,Whh0,2);  LD1(wa,Whh0,3);
    LD1(wa,Whh0,4);  LD1(wa,Whh0,5);  LD1(wa,Whh0,6);  LD1(wa,Whh0,7);
    LD1(wa,Whh0,8);  LD1(wa,Whh0,9);  LD1(wa,Whh0,10); LD1(wa,Whh0,11);
    LD1(wa,Whh0,12); LD1(wa,Whh0,13); LD1(wa,Whh0,14); LD1(wa,Whh0,15);
    LD1(wi,Wih1,0);  LD1(wi,Wih1,1);  LD1(wi,Wih1,2);  LD1(wi,Wih1,3);
    LD1(wi,Wih1,4);  LD1(wi,Wih1,5);  LD1(wi,Wih1,6);  LD1(wi,Wih1,7);
    LD1(wi,Wih1,8);  LD1(wi,Wih1,9);  LD1(wi,Wih1,10); LD1(wi,Wih1,11);
    LD1(wi,Wih1,12); LD1(wi,Wih1,13); LD1(wi,Wih1,14); LD1(wi,Wih1,15);
#undef LD1
#define PIN1(P, q) asm volatile("" : "+v"(P##q.x), "+v"(P##q.y), "+v"(P##q.z), "+v"(P##q.w))
    PIN1(wa,0);  PIN1(wa,1);  PIN1(wa,2);  PIN1(wa,3);
    PIN1(wa,4);  PIN1(wa,5);  PIN1(wa,6);  PIN1(wa,7);
    PIN1(wa,8);  PIN1(wa,9);  PIN1(wa,10); PIN1(wa,11);
    PIN1(wa,12); PIN1(wa,13); PIN1(wa,14); PIN1(wa,15);
    PIN1(wi,0);  PIN1(wi,1);  PIN1(wi,2);  PIN1(wi,3);
    PIN1(wi,4);  PIN1(wi,5);  PIN1(wi,6);  PIN1(wi,7);
    PIN1(wi,8);  PIN1(wi,9);  PIN1(wi,10); PIN1(wi,11);
    PIN1(wi,12); PIN1(wi,13); PIN1(wi,14); PIN1(wi,15);
#undef PIN1

    float* rowbase = seq + (long)c * TT * HH;        // pre0 in, h1 out (in-place)

    float pre_cur = 0.f, b1v = 0.f;
    if (tid < 64) { pre_cur = __builtin_nontemporal_load(&rowbase[J]); b1v = b1[J]; }

    __syncthreads();   // lds_w staged before first C2

    // prologue: h0[0] = tanh(pre0[0]); publish tag 1 (slot 0)
    if (tid < 64) {
        const float hv = tanhx(pre_cur);
        pub2(hbL0 + J, hbG0 + J, 1u, hv);
        pre_cur = __builtin_nontemporal_load(&rowbase[HH + J]);   // pre0[1]
    }
    float h1reg = 0.f;
    const float* lwcol = &lds_w[w << 6][lane];       // my k-block column in LDS

#define BC0(i) __uint_as_float(__builtin_amdgcn_readlane(h0bits, (i)))
#define BC1(i) __uint_as_float(__builtin_amdgcn_readlane(h1bits, (i)))

    for (int t = 0; t < TT; ++t) {
        // P3: poll h0[t] (tag t+1, slot t&1) — the one real wait per super-step
        const int so3 = ((t & 1) << 9) + (w << 6) + lane;
        const float h0new = poll2(hbL0 + so3, hbG0 + so3, (unsigned)(t + 1));
        const unsigned h0bits = __float_as_uint(h0new);

        if (t + 1 < TT) {   // C1: layer-0 step — the critical chain (reg-resident W)
            float a0 = 0.f, a1 = 0.f, a2 = 0.f, a3 = 0.f;
#define MACA(q) do { a0 = fmaf(BC0(4*q+0), wa##q.x, a0); a1 = fmaf(BC0(4*q+1), wa##q.y, a1); \
                     a2 = fmaf(BC0(4*q+2), wa##q.z, a2); a3 = fmaf(BC0(4*q+3), wa##q.w, a3); } while (0)
            MACA(0); MACA(1); MACA(2); MACA(3); MACA(4); MACA(5); MACA(6); MACA(7);
            MACA(8); MACA(9); MACA(10); MACA(11); MACA(12); MACA(13); MACA(14); MACA(15);
#undef MACA
            lds_a[(t + 1) & 1][w][lane] = (a0 + a1) + (a2 + a3);
            __syncthreads();
            if (tid < 64) {
                float s = pre_cur;
                #pragma unroll
                for (int q = 0; q < 8; ++q) s += lds_a[(t + 1) & 1][q][lane];
                const float hv = tanhx(s);
                const int sp = (((t + 1) & 1) << 9) + J;
                pub2(hbL0 + sp, hbG0 + sp, (unsigned)(t + 2), hv);            // publish ASAP
                if (t + 2 < TT) pre_cur = __builtin_nontemporal_load(&rowbase[(long)(t + 2) * HH + J]);
                if (t + 1 == TT - 1) __builtin_nontemporal_store(hv, &hTout[(c << 9) + J]);
            }
        }

        // P2: poll h1[t-1] (tag t, slot (t-1)&1) — published a full super-step ago
        if (t > 0) {
            const int so2 = (((t - 1) & 1) << 9) + (w << 6) + lane;
            h1reg = poll2(hbL1 + so2, hbG1 + so2, (unsigned)t);
        }
        const unsigned h1bits = __float_as_uint(h1reg);

        // C2: layer-1 step. Wih1 from regs (readlanes CSE with C1); Whh1 from LDS.
        {
            float a0 = 0.f, a1 = 0.f, a2 = 0.f, a3 = 0.f;
#define MACI(q) do { a0 = fmaf(BC0(4*q+0), wi##q.x, a0); a1 = fmaf(BC0(4*q+1), wi##q.y, a1); \
                     a2 = fmaf(BC0(4*q+2), wi##q.z, a2); a3 = fmaf(BC0(4*q+3), wi##q.w, a3); } while (0)
#define MACH(q) do { \
            a0 = fmaf(BC1(4*q+0), lwcol[(4*q+0)*64], a0); \
            a1 = fmaf(BC1(4*q+1), lwcol[(4*q+1)*64], a1); \
            a2 = fmaf(BC1(4*q+2), lwcol[(4*q+2)*64], a2); \
            a3 = fmaf(BC1(4*q+3), lwcol[(4*q+3)*64], a3); } while (0)
            MACI(0); MACI(1); MACI(2); MACI(3); MACI(4); MACI(5); MACI(6); MACI(7);
            MACI(8); MACI(9); MACI(10); MACI(11); MACI(12); MACI(13); MACI(14); MACI(15);
            MACH(0); MACH(1); MACH(2); MACH(3); MACH(4); MACH(5); MACH(6); MACH(7);
            MACH(8); MACH(9); MACH(10); MACH(11); MACH(12); MACH(13); MACH(14); MACH(15);
#undef MACH
#undef MACI
            lds_b[t & 1][w][lane] = (a0 + a1) + (a2 + a3);
            __syncthreads();
            if (tid < 64) {
                float s2 = b1v;
                #pragma unroll
                for (int q = 0; q < 8; ++q) s2 += lds_b[t & 1][q][lane];
                const float h1v = tanhx(s2);
                __builtin_nontemporal_store(h1v, &rowbase[(long)t * HH + J]);  // output
                if (t + 1 < TT) {
                    const int sp = ((t & 1) << 9) + J;
                    pub2(hbL1 + sp, hbG1 + sp, (unsigned)(t + 1), h1v);
                } else {
                    __builtin_nontemporal_store(h1v, &hTout[(BB << 9) + (c << 9) + J]);
                }
            }
        }
    }
#undef BC1
#undef BC0
}

extern "C" void kernel_launch(void* const* d_in, const int* in_sizes, int n_in,
                              void* d_out, int out_size, void* d_ws, size_t ws_size,
                              hipStream_t stream) {
    const float* x    = (const float*)d_in[0];
    const float* Wih0 = (const float*)d_in[1];
    const float* Whh0 = (const float*)d_in[2];
    const float* b0   = (const float*)d_in[3];
    const float* Wih1 = (const float*)d_in[4];
    const float* Whh1 = (const float*)d_in[5];
    const float* b1   = (const float*)d_in[6];

    float* out = (float*)d_out;                       // [B,T,H] (h1 seq) + [2,B,H] (hT)
    float* hT  = out + (size_t)BB * TT * HH;

    // ws: 4 x 256KB = 1MB: hbG0, hbG1, hbL2_0, hbL2_1. memset all each call (replays
    // reuse ws; zero tags never match wants; stale hbL2 tag-hits are benign: same
    // inputs -> same values).
    unsigned long long* hb = (unsigned long long*)d_ws;
    (void)hipMemsetAsync(d_ws, 0, (size_t)4 * BB * 2 * HH * sizeof(unsigned long long), stream);

    // 1) pre0 = x @ W_ih0 + b0  -> d_out main region (consumed in-place by fused_recur)
    ih_gemm<256><<<dim3((BB * TT) / 32), dim3(256), 0, stream>>>(x, Wih0, b0, out);
    // 2) fused 2-layer recurrence: h1 seq -> d_out (in-place over pre0), hT tails
    fused_recur<<<dim3(256), dim3(512), 0, stream>>>(Whh0, Wih1, Whh1, b1,
                                                     out, hT, hb);
}

// Round 16
// 4676.907 us; speedup vs baseline: 1.7464x; 1.7464x over previous
//
#include <hip/hip_runtime.h>
#include <math.h>

#define TT 2048
#define BB 32
#define HH 512

// ---------------- input-projection GEMM: OUT[r,:] = X[r,:]@W + bias ----------------
template<int K>
__global__ void __launch_bounds__(256)
ih_gemm(const float* X, const float* __restrict__ W,
        const float* __restrict__ bias, float* OUT)
{
    __shared__ float xt[32][K];
    const int wg  = (int)blockIdx.x;
    const int tid = (int)threadIdx.x;
    const long row0 = (long)wg * 32;

    {   // stage 32 rows of X (coalesced float4)
        const float4* Xv = (const float4*)(X + row0 * K);
        float4* xtv = (float4*)(&xt[0][0]);
        const int n4 = 8 * K;
        for (int i = tid; i < n4; i += 256) xtv[i] = Xv[i];
    }
    __syncthreads();

    const int j2 = tid * 2;
    float acc0[32], acc1[32];
    #pragma unroll
    for (int r = 0; r < 32; ++r) { acc0[r] = 0.f; acc1[r] = 0.f; }

    for (int k = 0; k < K; k += 4) {
        const float2 w0 = *(const float2*)&W[(k+0)*HH + j2];
        const float2 w1 = *(const float2*)&W[(k+1)*HH + j2];
        const float2 w2 = *(const float2*)&W[(k+2)*HH + j2];
        const float2 w3 = *(const float2*)&W[(k+3)*HH + j2];
        #pragma unroll
        for (int r = 0; r < 32; ++r) {
            const float4 xv = *(const float4*)&xt[r][k];
            acc0[r] += xv.x*w0.x + xv.y*w1.x + xv.z*w2.x + xv.w*w3.x;
            acc1[r] += xv.x*w0.y + xv.y*w1.y + xv.z*w2.y + xv.w*w3.y;
        }
    }
    const float2 bv = *(const float2*)&bias[j2];
    #pragma unroll
    for (int r = 0; r < 32; ++r) {
        float2 o; o.x = acc0[r] + bv.x; o.y = acc1[r] + bv.y;
        *(float2*)&OUT[(row0 + r) * HH + j2] = o;
    }
}

// ---------------- fused 2-layer persistent recurrence ----------------
// r9 kernel VERBATIM (best measured: fused 4114us, passed) except pollv:
// 4-deep pipelined sampling. The poll loop was a dependent load->cmp->branch chain
// sampling once per RTT (~700-900cy) -> expected discovery delay ~1.5xRTT ~ the
// unexplained 0.8us/superstep. Four INDEPENDENT loads issue back-to-back (vmcnt
// tracks each), checks drain oldest-first -> 4 samples in flight, discovery delay
// ~RTT + RTT/8. Any matching sample is THE value (tag uniquely identifies content;
// slot transitions once per 2 steps) -> correctness unchanged.
static __device__ __forceinline__ float tanhx(float s) {
    const float e = __expf(2.0f * s);
    return 1.0f - 2.0f / (e + 1.0f);
}
static __device__ __forceinline__ void pub(unsigned long long* p, unsigned tag, float v) {
    __hip_atomic_store(p, ((unsigned long long)tag << 32) | (unsigned long long)__float_as_uint(v),
                       __ATOMIC_RELAXED, __HIP_MEMORY_SCOPE_AGENT);
}
static __device__ __forceinline__ float pollv(unsigned long long* p, unsigned want) {
    for (;;) {
        unsigned long long p0 = __hip_atomic_load(p, __ATOMIC_RELAXED, __HIP_MEMORY_SCOPE_AGENT);
        unsigned long long p1 = __hip_atomic_load(p, __ATOMIC_RELAXED, __HIP_MEMORY_SCOPE_AGENT);
        unsigned long long p2 = __hip_atomic_load(p, __ATOMIC_RELAXED, __HIP_MEMORY_SCOPE_AGENT);
        unsigned long long p3 = __hip_atomic_load(p, __ATOMIC_RELAXED, __HIP_MEMORY_SCOPE_AGENT);
        if ((unsigned)(p0 >> 32) == want) return __uint_as_float((unsigned)p0);
        if ((unsigned)(p1 >> 32) == want) return __uint_as_float((unsigned)p1);
        if ((unsigned)(p2 >> 32) == want) return __uint_as_float((unsigned)p2);
        if ((unsigned)(p3 >> 32) == want) return __uint_as_float((unsigned)p3);
    }
}

__global__ void __attribute__((amdgpu_flat_work_group_size(512, 512),
                               amdgpu_waves_per_eu(2, 2)))
fused_recur(const float* __restrict__ Whh0, const float* __restrict__ Wih1,
            const float* __restrict__ Whh1, const float* __restrict__ b1,
            float* __restrict__ seq, float* __restrict__ hTout,
            unsigned long long* __restrict__ hb0, unsigned long long* __restrict__ hb1)
{
    __shared__ float lds_a[2][8][64];
    __shared__ float lds_b[2][8][64];
    const int bid  = (int)blockIdx.x;
    const int c    = bid & 31;      // chain; 8 slices of chain c share bid%8
    const int x    = bid >> 5;      // col-slice 0..7
    const int tid  = (int)threadIdx.x;
    const int lane = tid & 63;
    const int w    = tid >> 6;      // wave id == k-group
    const int J    = (x << 6) + lane;
    const long wb  = (long)(w << 6) * HH + J;   // &M[(w*64+kk)*HH + J], kk stride HH

    // ---- three W slices, 48 named float4s (192 VGPRs), pinned ----
    float4 wa0,wa1,wa2,wa3,wa4,wa5,wa6,wa7,wa8,wa9,wa10,wa11,wa12,wa13,wa14,wa15;  // Whh0
    float4 wi0,wi1,wi2,wi3,wi4,wi5,wi6,wi7,wi8,wi9,wi10,wi11,wi12,wi13,wi14,wi15;  // Wih1
    float4 wh0,wh1,wh2,wh3,wh4,wh5,wh6,wh7,wh8,wh9,wh10,wh11,wh12,wh13,wh14,wh15;  // Whh1
#define LD1(P, M, q) do { \
        P##q.x = M[wb + (4*q+0)*HH]; P##q.y = M[wb + (4*q+1)*HH]; \
        P##q.z = M[wb + (4*q+2)*HH]; P##q.w = M[wb + (4*q+3)*HH]; } while (0)
#define LD16(P, M) do { LD1(P,M,0); LD1(P,M,1); LD1(P,M,2); LD1(P,M,3); \
        LD1(P,M,4); LD1(P,M,5); LD1(P,M,6); LD1(P,M,7); LD1(P,M,8); LD1(P,M,9); \
        LD1(P,M,10); LD1(P,M,11); LD1(P,M,12); LD1(P,M,13); LD1(P,M,14); LD1(P,M,15); } while (0)
    LD16(wa, Whh0); LD16(wi, Wih1); LD16(wh, Whh1);
#undef LD16
#undef LD1
#define PIN1(P, q) asm volatile("" : "+v"(P##q.x), "+v"(P##q.y), "+v"(P##q.z), "+v"(P##q.w))
#define PIN16(P) do { PIN1(P,0); PIN1(P,1); PIN1(P,2); PIN1(P,3); PIN1(P,4); PIN1(P,5); \
        PIN1(P,6); PIN1(P,7); PIN1(P,8); PIN1(P,9); PIN1(P,10); PIN1(P,11); PIN1(P,12); \
        PIN1(P,13); PIN1(P,14); PIN1(P,15); } while (0)
    PIN16(wa); PIN16(wi); PIN16(wh);
#undef PIN16
#undef PIN1

    unsigned long long* hbc0 = hb0 + c * (2 * HH);   // [2][512] packed {tag|val}
    unsigned long long* hbc1 = hb1 + c * (2 * HH);
    float* rowbase = seq + (long)c * TT * HH;        // pre0 in, h1 out (in-place)

    float pre_cur = 0.f, b1v = 0.f;
    if (tid < 64) { pre_cur = rowbase[J]; b1v = b1[J]; }

    // prologue: h0[0] = tanh(pre0[0] + 0); publish tag 1 (slot 0)
    if (tid < 64) {
        const float hv = tanhx(pre_cur);
        pub(hbc0 + J, 1u, hv);
        pre_cur = rowbase[HH + J];                   // pre0[1]
    }
    float h1reg = 0.f;

#define BC0(i) __uint_as_float(__builtin_amdgcn_readlane(h0bits, (i)))
#define BC1(i) __uint_as_float(__builtin_amdgcn_readlane(h1bits, (i)))

    for (int t = 0; t < TT; ++t) {
        // P3: poll h0[t] (tag t+1, slot t&1) — the one real RTT wait per super-step
        const float h0new = pollv(hbc0 + ((t & 1) << 9) + (w << 6) + lane, (unsigned)(t + 1));
        const unsigned h0bits = __float_as_uint(h0new);

        if (t + 1 < TT) {   // C1(t+1): layer-0 step — the critical chain
            float a0 = 0.f, a1 = 0.f, a2 = 0.f, a3 = 0.f;
#define MACA(q) do { a0 = fmaf(BC0(4*q+0), wa##q.x, a0); a1 = fmaf(BC0(4*q+1), wa##q.y, a1); \
                     a2 = fmaf(BC0(4*q+2), wa##q.z, a2); a3 = fmaf(BC0(4*q+3), wa##q.w, a3); } while (0)
            MACA(0); MACA(1); MACA(2); MACA(3); MACA(4); MACA(5); MACA(6); MACA(7);
            MACA(8); MACA(9); MACA(10); MACA(11); MACA(12); MACA(13); MACA(14); MACA(15);
#undef MACA
            lds_a[(t + 1) & 1][w][lane] = (a0 + a1) + (a2 + a3);
            __syncthreads();
            if (tid < 64) {
                float s = pre_cur;
                #pragma unroll
                for (int q = 0; q < 8; ++q) s += lds_a[(t + 1) & 1][q][lane];
                const float hv = tanhx(s);
                pub(hbc0 + (((t + 1) & 1) << 9) + J, (unsigned)(t + 2), hv);  // publish ASAP
                if (t + 2 < TT) pre_cur = rowbase[(long)(t + 2) * HH + J];
                if (t + 1 == TT - 1) hTout[(c << 9) + J] = hv;                // hT layer 0
            }
        }

        // P2: poll h1[t-1] (tag t, slot (t-1)&1) — published a full super-step ago
        if (t > 0)
            h1reg = pollv(hbc1 + (((t - 1) & 1) << 9) + (w << 6) + lane, (unsigned)t);
        const unsigned h1bits = __float_as_uint(h1reg);

        // C2(t): layer-1 step — fills the next P3's RTT window
        {
            float a0 = 0.f, a1 = 0.f, a2 = 0.f, a3 = 0.f;
#define MACI(q) do { a0 = fmaf(BC0(4*q+0), wi##q.x, a0); a1 = fmaf(BC0(4*q+1), wi##q.y, a1); \
                     a2 = fmaf(BC0(4*q+2), wi##q.z, a2); a3 = fmaf(BC0(4*q+3), wi##q.w, a3); } while (0)
#define MACH(q) do { a0 = fmaf(BC1(4*q+0), wh##q.x, a0); a1 = fmaf(BC1(4*q+1), wh##q.y, a1); \
                     a2 = fmaf(BC1(4*q+2), wh##q.z, a2); a3 = fmaf(BC1(4*q+3), wh##q.w, a3); } while (0)
            MACI(0); MACI(1); MACI(2); MACI(3); MACI(4); MACI(5); MACI(6); MACI(7);
            MACI(8); MACI(9); MACI(10); MACI(11); MACI(12); MACI(13); MACI(14); MACI(15);
            MACH(0); MACH(1); MACH(2); MACH(3); MACH(4); MACH(5); MACH(6); MACH(7);
            MACH(8); MACH(9); MACH(10); MACH(11); MACH(12); MACH(13); MACH(14); MACH(15);
#undef MACH
#undef MACI
            lds_b[t & 1][w][lane] = (a0 + a1) + (a2 + a3);
            __syncthreads();
            if (tid < 64) {
                float s2 = b1v;
                #pragma unroll
                for (int q = 0; q < 8; ++q) s2 += lds_b[t & 1][q][lane];
                const float h1v = tanhx(s2);
                rowbase[(long)t * HH + J] = h1v;                   // THE output (h1 seq)
                if (t + 1 < TT) pub(hbc1 + ((t & 1) << 9) + J, (unsigned)(t + 1), h1v);
                else hTout[(BB << 9) + (c << 9) + J] = h1v;        // hT layer 1
            }
        }
    }
#undef BC1
#undef BC0
}

extern "C" void kernel_launch(void* const* d_in, const int* in_sizes, int n_in,
                              void* d_out, int out_size, void* d_ws, size_t ws_size,
                              hipStream_t stream) {
    const float* x    = (const float*)d_in[0];
    const float* Wih0 = (const float*)d_in[1];
    const float* Whh0 = (const float*)d_in[2];
    const float* b0   = (const float*)d_in[3];
    const float* Wih1 = (const float*)d_in[4];
    const float* Whh1 = (const float*)d_in[5];
    const float* b1   = (const float*)d_in[6];

    float* out = (float*)d_out;                       // [B,T,H] (h1 seq) + [2,B,H] (hT)
    float* hT  = out + (size_t)BB * TT * HH;

    // ws: hb0 [32][2][512]x8B = 256K, hb1 same at +256K. memset both each call:
    // graph replays reuse ws un-poisoned and stale tags would alias wanted tags.
    unsigned long long* hb0 = (unsigned long long*)d_ws;
    unsigned long long* hb1 = hb0 + (size_t)BB * 2 * HH;
    (void)hipMemsetAsync(d_ws, 0, (size_t)2 * BB * 2 * HH * sizeof(unsigned long long), stream);

    // 1) pre0 = x @ W_ih0 + b0  -> d_out main region (consumed in-place by fused_recur)
    ih_gemm<256><<<dim3((BB * TT) / 32), dim3(256), 0, stream>>>(x, Wih0, b0, out);
    // 2) fused 2-layer recurrence: h1 seq -> d_out (in-place over pre0), hT tails
    fused_recur<<<dim3(256), dim3(512), 0, stream>>>(Whh0, Wih1, Whh1, b1,
                                                     out, hT, hb0, hb1);
}

// Round 17
// 3666.376 us; speedup vs baseline: 2.2278x; 1.2756x over previous
//
#include <hip/hip_runtime.h>
#include <math.h>

#define TT 2048
#define BB 32
#define HH 512

// ---------------- input-projection GEMM: OUT[r,:] = X[r,:]@W + bias ----------------
template<int K>
__global__ void __launch_bounds__(256)
ih_gemm(const float* X, const float* __restrict__ W,
        const float* __restrict__ bias, float* OUT)
{
    __shared__ float xt[32][K];
    const int wg  = (int)blockIdx.x;
    const int tid = (int)threadIdx.x;
    const long row0 = (long)wg * 32;

    {   // stage 32 rows of X (coalesced float4)
        const float4* Xv = (const float4*)(X + row0 * K);
        float4* xtv = (float4*)(&xt[0][0]);
        const int n4 = 8 * K;
        for (int i = tid; i < n4; i += 256) xtv[i] = Xv[i];
    }
    __syncthreads();

    const int j2 = tid * 2;
    float acc0[32], acc1[32];
    #pragma unroll
    for (int r = 0; r < 32; ++r) { acc0[r] = 0.f; acc1[r] = 0.f; }

    for (int k = 0; k < K; k += 4) {
        const float2 w0 = *(const float2*)&W[(k+0)*HH + j2];
        const float2 w1 = *(const float2*)&W[(k+1)*HH + j2];
        const float2 w2 = *(const float2*)&W[(k+2)*HH + j2];
        const float2 w3 = *(const float2*)&W[(k+3)*HH + j2];
        #pragma unroll
        for (int r = 0; r < 32; ++r) {
            const float4 xv = *(const float4*)&xt[r][k];
            acc0[r] += xv.x*w0.x + xv.y*w1.x + xv.z*w2.x + xv.w*w3.x;
            acc1[r] += xv.x*w0.y + xv.y*w1.y + xv.z*w2.y + xv.w*w3.y;
        }
    }
    const float2 bv = *(const float2*)&bias[j2];
    #pragma unroll
    for (int r = 0; r < 32; ++r) {
        float2 o; o.x = acc0[r] + bv.x; o.y = acc1[r] + bv.y;
        *(float2*)&OUT[(row0 + r) * HH + j2] = o;
    }
}

// ---------------- fused 2-layer persistent recurrence ----------------
// r9 kernel VERBATIM (best measured: fused 4114us; r10-r16 storage/comm variants all
// lost) with ONE change: EARLY-ISSUED P2 SAMPLE. In r9, P2's first load cannot issue
// until after C1's __syncthreads (compiler cannot hoist an atomic load across a
// barrier), so P2 costs a full ~0.3us RTT even though h1[t-1] was published a whole
// superstep ago. Fix: issue the P2 sample right after P3 succeeds (before C1's MAC);
// its latency hides under C1 compute + barrier + publish. After C1, a tag-match uses
// the sample directly; a miss falls back to the proven pollv loop (correct for any
// timing; tag uniquely identifies content). Poll structure itself unchanged (r15/r16:
// poll-traffic tweaks inflate everyone's RTT and regress).
static __device__ __forceinline__ float tanhx(float s) {
    const float e = __expf(2.0f * s);
    return 1.0f - 2.0f / (e + 1.0f);
}
static __device__ __forceinline__ void pub(unsigned long long* p, unsigned tag, float v) {
    __hip_atomic_store(p, ((unsigned long long)tag << 32) | (unsigned long long)__float_as_uint(v),
                       __ATOMIC_RELAXED, __HIP_MEMORY_SCOPE_AGENT);
}
static __device__ __forceinline__ float pollv(unsigned long long* p, unsigned want) {
    unsigned long long pk = __hip_atomic_load(p, __ATOMIC_RELAXED, __HIP_MEMORY_SCOPE_AGENT);
    while ((unsigned)(pk >> 32) != want)
        pk = __hip_atomic_load(p, __ATOMIC_RELAXED, __HIP_MEMORY_SCOPE_AGENT);
    return __uint_as_float((unsigned)(pk & 0xffffffffu));
}

__global__ void __attribute__((amdgpu_flat_work_group_size(512, 512),
                               amdgpu_waves_per_eu(2, 2)))
fused_recur(const float* __restrict__ Whh0, const float* __restrict__ Wih1,
            const float* __restrict__ Whh1, const float* __restrict__ b1,
            float* __restrict__ seq, float* __restrict__ hTout,
            unsigned long long* __restrict__ hb0, unsigned long long* __restrict__ hb1)
{
    __shared__ float lds_a[2][8][64];
    __shared__ float lds_b[2][8][64];
    const int bid  = (int)blockIdx.x;
    const int c    = bid & 31;      // chain; 8 slices of chain c share bid%8
    const int x    = bid >> 5;      // col-slice 0..7
    const int tid  = (int)threadIdx.x;
    const int lane = tid & 63;
    const int w    = tid >> 6;      // wave id == k-group
    const int J    = (x << 6) + lane;
    const long wb  = (long)(w << 6) * HH + J;   // &M[(w*64+kk)*HH + J], kk stride HH

    // ---- three W slices, 48 named float4s (192 VGPRs), pinned ----
    float4 wa0,wa1,wa2,wa3,wa4,wa5,wa6,wa7,wa8,wa9,wa10,wa11,wa12,wa13,wa14,wa15;  // Whh0
    float4 wi0,wi1,wi2,wi3,wi4,wi5,wi6,wi7,wi8,wi9,wi10,wi11,wi12,wi13,wi14,wi15;  // Wih1
    float4 wh0,wh1,wh2,wh3,wh4,wh5,wh6,wh7,wh8,wh9,wh10,wh11,wh12,wh13,wh14,wh15;  // Whh1
#define LD1(P, M, q) do { \
        P##q.x = M[wb + (4*q+0)*HH]; P##q.y = M[wb + (4*q+1)*HH]; \
        P##q.z = M[wb + (4*q+2)*HH]; P##q.w = M[wb + (4*q+3)*HH]; } while (0)
#define LD16(P, M) do { LD1(P,M,0); LD1(P,M,1); LD1(P,M,2); LD1(P,M,3); \
        LD1(P,M,4); LD1(P,M,5); LD1(P,M,6); LD1(P,M,7); LD1(P,M,8); LD1(P,M,9); \
        LD1(P,M,10); LD1(P,M,11); LD1(P,M,12); LD1(P,M,13); LD1(P,M,14); LD1(P,M,15); } while (0)
    LD16(wa, Whh0); LD16(wi, Wih1); LD16(wh, Whh1);
#undef LD16
#undef LD1
#define PIN1(P, q) asm volatile("" : "+v"(P##q.x), "+v"(P##q.y), "+v"(P##q.z), "+v"(P##q.w))
#define PIN16(P) do { PIN1(P,0); PIN1(P,1); PIN1(P,2); PIN1(P,3); PIN1(P,4); PIN1(P,5); \
        PIN1(P,6); PIN1(P,7); PIN1(P,8); PIN1(P,9); PIN1(P,10); PIN1(P,11); PIN1(P,12); \
        PIN1(P,13); PIN1(P,14); PIN1(P,15); } while (0)
    PIN16(wa); PIN16(wi); PIN16(wh);
#undef PIN16
#undef PIN1

    unsigned long long* hbc0 = hb0 + c * (2 * HH);   // [2][512] packed {tag|val}
    unsigned long long* hbc1 = hb1 + c * (2 * HH);
    float* rowbase = seq + (long)c * TT * HH;        // pre0 in, h1 out (in-place)

    float pre_cur = 0.f, b1v = 0.f;
    if (tid < 64) { pre_cur = rowbase[J]; b1v = b1[J]; }

    // prologue: h0[0] = tanh(pre0[0] + 0); publish tag 1 (slot 0)
    if (tid < 64) {
        const float hv = tanhx(pre_cur);
        pub(hbc0 + J, 1u, hv);
        pre_cur = rowbase[HH + J];                   // pre0[1]
    }
    float h1reg = 0.f;

#define BC0(i) __uint_as_float(__builtin_amdgcn_readlane(h0bits, (i)))
#define BC1(i) __uint_as_float(__builtin_amdgcn_readlane(h1bits, (i)))

    for (int t = 0; t < TT; ++t) {
        // P3: poll h0[t] (tag t+1, slot t&1) — the one real RTT wait per super-step
        const float h0new = pollv(hbc0 + ((t & 1) << 9) + (w << 6) + lane, (unsigned)(t + 1));
        const unsigned h0bits = __float_as_uint(h0new);

        // EARLY P2 sample: issue now; RTT hides under C1 (check after C1's barrier).
        unsigned long long* p2slot = hbc1 + (((t - 1) & 1) << 9) + (w << 6) + lane;
        unsigned long long p2s = 0;
        if (t > 0)
            p2s = __hip_atomic_load(p2slot, __ATOMIC_RELAXED, __HIP_MEMORY_SCOPE_AGENT);

        if (t + 1 < TT) {   // C1(t+1): layer-0 step — the critical chain
            float a0 = 0.f, a1 = 0.f, a2 = 0.f, a3 = 0.f;
#define MACA(q) do { a0 = fmaf(BC0(4*q+0), wa##q.x, a0); a1 = fmaf(BC0(4*q+1), wa##q.y, a1); \
                     a2 = fmaf(BC0(4*q+2), wa##q.z, a2); a3 = fmaf(BC0(4*q+3), wa##q.w, a3); } while (0)
            MACA(0); MACA(1); MACA(2); MACA(3); MACA(4); MACA(5); MACA(6); MACA(7);
            MACA(8); MACA(9); MACA(10); MACA(11); MACA(12); MACA(13); MACA(14); MACA(15);
#undef MACA
            lds_a[(t + 1) & 1][w][lane] = (a0 + a1) + (a2 + a3);
            __syncthreads();
            if (tid < 64) {
                float s = pre_cur;
                #pragma unroll
                for (int q = 0; q < 8; ++q) s += lds_a[(t + 1) & 1][q][lane];
                const float hv = tanhx(s);
                pub(hbc0 + (((t + 1) & 1) << 9) + J, (unsigned)(t + 2), hv);  // publish ASAP
                if (t + 2 < TT) pre_cur = rowbase[(long)(t + 2) * HH + J];
                if (t + 1 == TT - 1) hTout[(c << 9) + J] = hv;                // hT layer 0
            }
        }

        // P2 resolve: common case = early sample already tagged (published a full
        // superstep ago); rare miss -> proven fallback poll.
        if (t > 0) {
            if ((unsigned)(p2s >> 32) == (unsigned)t)
                h1reg = __uint_as_float((unsigned)(p2s & 0xffffffffu));
            else
                h1reg = pollv(p2slot, (unsigned)t);
        }
        const unsigned h1bits = __float_as_uint(h1reg);

        // C2(t): layer-1 step — fills the next P3's RTT window
        {
            float a0 = 0.f, a1 = 0.f, a2 = 0.f, a3 = 0.f;
#define MACI(q) do { a0 = fmaf(BC0(4*q+0), wi##q.x, a0); a1 = fmaf(BC0(4*q+1), wi##q.y, a1); \
                     a2 = fmaf(BC0(4*q+2), wi##q.z, a2); a3 = fmaf(BC0(4*q+3), wi##q.w, a3); } while (0)
#define MACH(q) do { a0 = fmaf(BC1(4*q+0), wh##q.x, a0); a1 = fmaf(BC1(4*q+1), wh##q.y, a1); \
                     a2 = fmaf(BC1(4*q+2), wh##q.z, a2); a3 = fmaf(BC1(4*q+3), wh##q.w, a3); } while (0)
            MACI(0); MACI(1); MACI(2); MACI(3); MACI(4); MACI(5); MACI(6); MACI(7);
            MACI(8); MACI(9); MACI(10); MACI(11); MACI(12); MACI(13); MACI(14); MACI(15);
            MACH(0); MACH(1); MACH(2); MACH(3); MACH(4); MACH(5); MACH(6); MACH(7);
            MACH(8); MACH(9); MACH(10); MACH(11); MACH(12); MACH(13); MACH(14); MACH(15);
#undef MACH
#undef MACI
            lds_b[t & 1][w][lane] = (a0 + a1) + (a2 + a3);
            __syncthreads();
            if (tid < 64) {
                float s2 = b1v;
                #pragma unroll
                for (int q = 0; q < 8; ++q) s2 += lds_b[t & 1][q][lane];
                const float h1v = tanhx(s2);
                rowbase[(long)t * HH + J] = h1v;                   // THE output (h1 seq)
                if (t + 1 < TT) pub(hbc1 + ((t & 1) << 9) + J, (unsigned)(t + 1), h1v);
                else hTout[(BB << 9) + (c << 9) + J] = h1v;        // hT layer 1
            }
        }
    }
#undef BC1
#undef BC0
}

extern "C" void kernel_launch(void* const* d_in, const int* in_sizes, int n_in,
                              void* d_out, int out_size, void* d_ws, size_t ws_size,
                              hipStream_t stream) {
    const float* x    = (const float*)d_in[0];
    const float* Wih0 = (const float*)d_in[1];
    const float* Whh0 = (const float*)d_in[2];
    const float* b0   = (const float*)d_in[3];
    const float* Wih1 = (const float*)d_in[4];
    const float* Whh1 = (const float*)d_in[5];
    const float* b1   = (const float*)d_in[6];

    float* out = (float*)d_out;                       // [B,T,H] (h1 seq) + [2,B,H] (hT)
    float* hT  = out + (size_t)BB * TT * HH;

    // ws: hb0 [32][2][512]x8B = 256K, hb1 same at +256K. memset both each call:
    // graph replays reuse ws un-poisoned and stale tags would alias wanted tags.
    unsigned long long* hb0 = (unsigned long long*)d_ws;
    unsigned long long* hb1 = hb0 + (size_t)BB * 2 * HH;
    (void)hipMemsetAsync(d_ws, 0, (size_t)2 * BB * 2 * HH * sizeof(unsigned long long), stream);

    // 1) pre0 = x @ W_ih0 + b0  -> d_out main region (consumed in-place by fused_recur)
    ih_gemm<256><<<dim3((BB * TT) / 32), dim3(256), 0, stream>>>(x, Wih0, b0, out);
    // 2) fused 2-layer recurrence: h1 seq -> d_out (in-place over pre0), hT tails
    fused_recur<<<dim3(256), dim3(512), 0, stream>>>(Whh0, Wih1, Whh1, b1,
                                                     out, hT, hb0, hb1);
}